// Round 2
// baseline (2244.127 us; speedup 1.0000x reference)
//
#include <hip/hip_runtime.h>
#include <stdint.h>

#define N_PTS  16384
#define B_SZ   4
#define K_S    1024   // SAMPLE_NUM
#define K_N    32     // NEIGHBOR_NUM
#define C_FEAT 128

// ---------------- Threefry-2x32 (JAX-compatible) ----------------
__device__ inline void threefry2x32(uint32_t k0, uint32_t k1,
                                    uint32_t x0, uint32_t x1,
                                    uint32_t& o0, uint32_t& o1) {
  uint32_t ks[3] = {k0, k1, k0 ^ k1 ^ 0x1BD11BDAu};
  const uint32_t rot[2][4] = {{13u, 15u, 26u, 6u}, {17u, 29u, 16u, 24u}};
  x0 += ks[0];
  x1 += ks[1];
#pragma unroll
  for (int i = 0; i < 5; ++i) {
    const uint32_t* r = rot[i & 1];
#pragma unroll
    for (int j = 0; j < 4; ++j) {
      x0 += x1;
      x1 = (x1 << r[j]) | (x1 >> (32u - r[j]));
      x1 ^= x0;
    }
    x0 += ks[(i + 1) % 3];
    x1 += ks[(i + 2) % 3] + (uint32_t)(i + 1);
  }
  o0 = x0;
  o1 = x1;
}

// jax.random.randint(jax.random.key(42), (B,), 0, N), threefry_partitionable:
//   _randint: k1, k2 = split(key); span = 16384 (pow2) ->
//     multiplier = (2^16 % span)^2 % span = 0  ->  result = lower_bits % span
//   lower_bits come from k2 (the SECOND subkey).
//   fold-like split: subkey[i] = threefry_block(key, (0, i)) -> k2 = TF((0,42),(0,1))
//   random_bits 32: bits[b] = fold(threefry_block(k2, (0, b))) = y0 ^ y1
__device__ inline int fps_start_index(int b) {
  uint32_t c0, c1, h0, h1;
  threefry2x32(0u, 42u, 0u, 1u, c0, c1);              // k2 = split(key)[1]
  threefry2x32(c0, c1, 0u, (uint32_t)b, h0, h1);      // lower_bits[b]
  return (int)((h0 ^ h1) & (uint32_t)(N_PTS - 1));    // % span (pow2)
}

// ---------------- FPS: one block per batch ----------------
#define FT  512
#define PPT (N_PTS / FT)  // 32 points per thread

__global__ __launch_bounds__(FT, 1) void fps_kernel(
    const float* __restrict__ xyz, float* __restrict__ sample_xyz) {
  const int b = blockIdx.x;
  const int t = threadIdx.x;
  const int lane = t & 63;
  const int wv = t >> 6;
  const float* bx = xyz + (size_t)b * N_PTS * 3;

  // per-thread point set: p = j*FT + t
  float px[PPT], py[PPT], pz[PPT], md[PPT];
#pragma unroll
  for (int j = 0; j < PPT; ++j) {
    const int p = j * FT + t;
    px[j] = bx[p * 3 + 0];
    py[j] = bx[p * 3 + 1];
    pz[j] = bx[p * 3 + 2];
    md[j] = __int_as_float(0x7f800000);  // +inf
  }

  __shared__ float cur[3];
  __shared__ unsigned long long wkey[FT / 64];

  int cur_p = fps_start_index(b);

  for (int s = 0; s < K_S; ++s) {
    // owner thread publishes current point's coords; also emits the sample
    if ((cur_p & (FT - 1)) == t) {
      const int jj = cur_p >> 9;  // log2(FT)
      float cx = 0.f, cy = 0.f, cz = 0.f;
#pragma unroll
      for (int j = 0; j < PPT; ++j)
        if (j == jj) { cx = px[j]; cy = py[j]; cz = pz[j]; }
      cur[0] = cx; cur[1] = cy; cur[2] = cz;
      float* o = sample_xyz + ((size_t)b * K_S + s) * 3;
      o[0] = cx; o[1] = cy; o[2] = cz;
    }
    __syncthreads();
    const float lx = cur[0], ly = cur[1], lz = cur[2];

    // update min_d2 and track local argmax (first-index tie-break via strict >)
    float bestv = -1.0f;
    int bestp = 0;
#pragma unroll
    for (int j = 0; j < PPT; ++j) {
      const float dx = __fsub_rn(px[j], lx);
      const float dy = __fsub_rn(py[j], ly);
      const float dz = __fsub_rn(pz[j], lz);
      // XLA order: ((dx*dx + dy*dy) + dz*dz), no FMA contraction
      const float d2 = __fadd_rn(
          __fadd_rn(__fmul_rn(dx, dx), __fmul_rn(dy, dy)), __fmul_rn(dz, dz));
      const float m = fminf(md[j], d2);
      md[j] = m;
      if (m > bestv) { bestv = m; bestp = j * FT + t; }
    }

    // pack: value bits (monotonic for >=0 floats) high, inverted index low
    unsigned long long key =
        ((unsigned long long)__float_as_uint(bestv) << 32) |
        (unsigned long long)(0xFFFFFFFFu - (uint32_t)bestp);
#pragma unroll
    for (int off = 32; off >= 1; off >>= 1) {
      const unsigned long long o = __shfl_xor(key, off, 64);
      key = (o > key) ? o : key;
    }
    if (lane == 0) wkey[wv] = key;
    __syncthreads();

    unsigned long long best = wkey[0];
#pragma unroll
    for (int w = 1; w < FT / 64; ++w) {
      const unsigned long long o = wkey[w];
      best = (o > best) ? o : best;
    }
    cur_p = (int)(0xFFFFFFFFu - (uint32_t)(best & 0xFFFFFFFFull));
  }
}

// ---------------- Ball query + gather: one wave per query ----------------
__global__ __launch_bounds__(256) void group_kernel(
    const float* __restrict__ xyz, const float* __restrict__ feat,
    const float* __restrict__ sample_xyz, float* __restrict__ out_feat) {
  const int lane = threadIdx.x & 63;
  const int wv = threadIdx.x >> 6;
  const int q = blockIdx.x * 4 + wv;  // 0..4095
  const int b = q >> 10;

  __shared__ int idxs[4][K_N];

  const float qx = sample_xyz[q * 3 + 0];
  const float qy = sample_xyz[q * 3 + 1];
  const float qz = sample_xyz[q * 3 + 2];
  const float* bx = xyz + (size_t)b * N_PTS * 3;
  const float R2 = (float)(0.2 * 0.2);  // f32 round of the Python double

  int cnt = 0;
  for (int c = 0; c < N_PTS / 64 && cnt < K_N; ++c) {
    const int p = c * 64 + lane;
    const float x = bx[p * 3 + 0];
    const float y = bx[p * 3 + 1];
    const float z = bx[p * 3 + 2];
    const float dx = __fsub_rn(qx, x);
    const float dy = __fsub_rn(qy, y);
    const float dz = __fsub_rn(qz, z);
    const float d2 = __fadd_rn(
        __fadd_rn(__fmul_rn(dx, dx), __fmul_rn(dy, dy)), __fmul_rn(dz, dz));
    const bool hit = d2 < R2;
    const unsigned long long m = __ballot(hit);
    if (hit) {
      const int slot = cnt + __popcll(m & ((1ull << lane) - 1ull));
      if (slot < K_N) idxs[wv][slot] = p;
    }
    cnt += (int)__popcll(m);
  }
  // -1 padding semantics: gather_feat maps -1 -> row SAMPLE_NUM (=1024)
  if (cnt < K_N) {
    for (int s2 = cnt + lane; s2 < K_N; s2 += 64) idxs[wv][s2] = K_S;
  }
  __syncthreads();

  // gather feat rows -> out[(q*32 + k)*128 + c], float4 coalesced
  const float4* f4 = (const float4*)feat;
  float4* o4 = (float4*)out_feat;
  const size_t fbase = (size_t)b * N_PTS * (C_FEAT / 4);
  const size_t obase = (size_t)q * K_N * (C_FEAT / 4);
  const int c4 = lane & 31;
  const int khalf = lane >> 5;
#pragma unroll 4
  for (int kk = 0; kk < K_N; kk += 2) {
    const int k = kk + khalf;
    const int id = idxs[wv][k];
    const float4 v = f4[fbase + (size_t)id * (C_FEAT / 4) + c4];
    o4[obase + (size_t)k * (C_FEAT / 4) + c4] = v;
  }
}

extern "C" void kernel_launch(void* const* d_in, const int* in_sizes, int n_in,
                              void* d_out, int out_size, void* d_ws,
                              size_t ws_size, hipStream_t stream) {
  const float* xyz = (const float*)d_in[0];
  const float* feat = (const float*)d_in[1];
  float* sample_xyz = (float*)d_out;
  float* out_feat = (float*)d_out + (size_t)B_SZ * K_S * 3;

  hipLaunchKernelGGL(fps_kernel, dim3(B_SZ), dim3(FT), 0, stream, xyz,
                     sample_xyz);
  hipLaunchKernelGGL(group_kernel, dim3((B_SZ * K_S) / 4), dim3(256), 0,
                     stream, xyz, feat, sample_xyz, out_feat);
}

// Round 3
// 2023.046 us; speedup vs baseline: 1.1093x; 1.1093x over previous
//
#include <hip/hip_runtime.h>
#include <stdint.h>

#define N_PTS  16384
#define B_SZ   4
#define K_S    1024   // SAMPLE_NUM
#define K_N    32     // NEIGHBOR_NUM
#define C_FEAT 128

// ---------------- Threefry-2x32 (JAX-compatible) ----------------
__device__ inline void threefry2x32(uint32_t k0, uint32_t k1,
                                    uint32_t x0, uint32_t x1,
                                    uint32_t& o0, uint32_t& o1) {
  uint32_t ks[3] = {k0, k1, k0 ^ k1 ^ 0x1BD11BDAu};
  const uint32_t rot[2][4] = {{13u, 15u, 26u, 6u}, {17u, 29u, 16u, 24u}};
  x0 += ks[0];
  x1 += ks[1];
#pragma unroll
  for (int i = 0; i < 5; ++i) {
    const uint32_t* r = rot[i & 1];
#pragma unroll
    for (int j = 0; j < 4; ++j) {
      x0 += x1;
      x1 = (x1 << r[j]) | (x1 >> (32u - r[j]));
      x1 ^= x0;
    }
    x0 += ks[(i + 1) % 3];
    x1 += ks[(i + 2) % 3] + (uint32_t)(i + 1);
  }
  o0 = x0;
  o1 = x1;
}

// jax.random.randint(key(42),(B,),0,N), threefry_partitionable:
// k2 = TF((0,42),(0,1)); bits[b] = fold(TF(k2,(0,b))); start = bits & 16383
__device__ inline int fps_start_index(int b) {
  uint32_t c0, c1, h0, h1;
  threefry2x32(0u, 42u, 0u, 1u, c0, c1);
  threefry2x32(c0, c1, 0u, (uint32_t)b, h0, h1);
  return (int)((h0 ^ h1) & (uint32_t)(N_PTS - 1));
}

// ---------------- FPS: one 1024-thread block per batch ----------------
// 16 waves = 4 waves/SIMD for latency hiding; ONE barrier per iteration via
// double-buffered per-wave argmax keys; winner coords re-fetched from global
// (broadcast load) instead of divergent register extraction.
#define FT  1024
#define PPT (N_PTS / FT)  // 16 points per thread

__global__ __launch_bounds__(FT) void fps_kernel(
    const float* __restrict__ xyz, float* __restrict__ sample_xyz) {
  const int b = blockIdx.x;
  const int t = threadIdx.x;
  const int lane = t & 63;
  const int wv = t >> 6;  // 0..15
  const float* bx = xyz + (size_t)b * N_PTS * 3;

  // per-thread point set: p = j*FT + t
  float px[PPT], py[PPT], pz[PPT], md[PPT];
#pragma unroll
  for (int j = 0; j < PPT; ++j) {
    const int p = j * FT + t;
    px[j] = bx[p * 3 + 0];
    py[j] = bx[p * 3 + 1];
    pz[j] = bx[p * 3 + 2];
    md[j] = __int_as_float(0x7f800000);  // +inf
  }

  __shared__ unsigned long long wkey[2][FT / 64];

  // prologue: seed buffer 0 with the start index as the "winner"
  {
    const int start = fps_start_index(b);
    if (lane == 0) wkey[0][wv] = 0ull;
    // owner thread overwrites its own wave's slot (same-wave program order)
    if (t == (start & (FT - 1)))
      wkey[0][wv] = (0xFFFFFFFFull << 32) |
                    (unsigned long long)(0xFFFFFFFFu - (uint32_t)start);
  }
  __syncthreads();

  for (int s = 0; s < K_S; ++s) {
    const int rb = s & 1, wb = rb ^ 1;

    // cross-wave argmax (redundant on all threads): 16 u64 keys
    unsigned long long best = wkey[rb][0];
#pragma unroll
    for (int w = 1; w < FT / 64; ++w) {
      const unsigned long long o = wkey[rb][w];
      best = (o > best) ? o : best;
    }
    const int cur = (int)(0xFFFFFFFFu - (uint32_t)best);

    // broadcast load of the selected point's coords (same addr wave-wide)
    const float cx = bx[cur * 3 + 0];
    const float cy = bx[cur * 3 + 1];
    const float cz = bx[cur * 3 + 2];

    // owner thread emits the sample
    if (t == (cur & (FT - 1))) {
      float* o = sample_xyz + ((size_t)b * K_S + s) * 3;
      o[0] = cx; o[1] = cy; o[2] = cz;
    }

    // min_d2 update + local argmax (first-index tie-break via strict >)
    float bestv = -1.0f;
    int bestj = 0;
#pragma unroll
    for (int j = 0; j < PPT; ++j) {
      const float dx = __fsub_rn(px[j], cx);
      const float dy = __fsub_rn(py[j], cy);
      const float dz = __fsub_rn(pz[j], cz);
      // XLA order: ((dx*dx + dy*dy) + dz*dz), no FMA contraction
      const float d2 = __fadd_rn(
          __fadd_rn(__fmul_rn(dx, dx), __fmul_rn(dy, dy)), __fmul_rn(dz, dz));
      const float m = fminf(md[j], d2);
      md[j] = m;
      if (m > bestv) { bestv = m; bestj = j; }
    }

    // pack: value bits high (monotonic for >=0 floats), inverted index low
    unsigned long long key =
        ((unsigned long long)__float_as_uint(bestv) << 32) |
        (unsigned long long)(0xFFFFFFFFu - (uint32_t)(bestj * FT + t));
#pragma unroll
    for (int off = 32; off >= 1; off >>= 1) {
      const unsigned long long o = __shfl_xor(key, off, 64);
      key = (o > key) ? o : key;
    }
    if (lane == 0) wkey[wb][wv] = key;
    __syncthreads();  // the ONE barrier per iteration
  }
}

// ---------------- Ball query + gather: one wave per query ----------------
__global__ __launch_bounds__(256) void group_kernel(
    const float* __restrict__ xyz, const float* __restrict__ feat,
    const float* __restrict__ sample_xyz, float* __restrict__ out_feat) {
  const int lane = threadIdx.x & 63;
  const int wv = threadIdx.x >> 6;
  const int q = blockIdx.x * 4 + wv;  // 0..4095
  const int b = q >> 10;

  __shared__ int idxs[4][K_N];

  const float qx = sample_xyz[q * 3 + 0];
  const float qy = sample_xyz[q * 3 + 1];
  const float qz = sample_xyz[q * 3 + 2];
  const float* bx = xyz + (size_t)b * N_PTS * 3;
  const float R2 = (float)(0.2 * 0.2);  // f32 round of the Python double
  const unsigned long long below = (1ull << lane) - 1ull;

  int cnt = 0;
  for (int c = 0; c < N_PTS / 128 && cnt < K_N; ++c) {
    const int p0 = c * 128 + lane;
    const int p1 = p0 + 64;
    const float x0 = bx[p0 * 3 + 0], y0 = bx[p0 * 3 + 1], z0 = bx[p0 * 3 + 2];
    const float x1 = bx[p1 * 3 + 0], y1 = bx[p1 * 3 + 1], z1 = bx[p1 * 3 + 2];

    const float dx0 = __fsub_rn(qx, x0), dy0 = __fsub_rn(qy, y0),
                dz0 = __fsub_rn(qz, z0);
    const float d20 = __fadd_rn(
        __fadd_rn(__fmul_rn(dx0, dx0), __fmul_rn(dy0, dy0)),
        __fmul_rn(dz0, dz0));
    const float dx1 = __fsub_rn(qx, x1), dy1 = __fsub_rn(qy, y1),
                dz1 = __fsub_rn(qz, z1);
    const float d21 = __fadd_rn(
        __fadd_rn(__fmul_rn(dx1, dx1), __fmul_rn(dy1, dy1)),
        __fmul_rn(dz1, dz1));

    const bool h0 = d20 < R2;
    const bool h1 = d21 < R2;
    const unsigned long long m0 = __ballot(h0);
    const unsigned long long m1 = __ballot(h1);
    const int c0 = (int)__popcll(m0);
    if (h0) {
      const int slot = cnt + (int)__popcll(m0 & below);
      if (slot < K_N) idxs[wv][slot] = p0;
    }
    if (h1) {
      const int slot = cnt + c0 + (int)__popcll(m1 & below);
      if (slot < K_N) idxs[wv][slot] = p1;
    }
    cnt += c0 + (int)__popcll(m1);
  }
  // -1 padding semantics: gather_feat maps -1 -> row SAMPLE_NUM (=1024)
  if (cnt < K_N) {
    for (int s2 = cnt + lane; s2 < K_N; s2 += 64) idxs[wv][s2] = K_S;
  }
  __syncthreads();

  // gather feat rows -> out[(q*32 + k)*128 + c], float4 coalesced, full unroll
  const float4* f4 = (const float4*)feat;
  float4* o4 = (float4*)out_feat;
  const size_t fbase = (size_t)b * N_PTS * (C_FEAT / 4);
  const size_t obase = (size_t)q * K_N * (C_FEAT / 4);
  const int c4 = lane & 31;
  const int khalf = lane >> 5;
#pragma unroll
  for (int kk = 0; kk < K_N; kk += 2) {
    const int k = kk + khalf;
    const int id = idxs[wv][k];
    const float4 v = f4[fbase + (size_t)id * (C_FEAT / 4) + c4];
    o4[obase + (size_t)k * (C_FEAT / 4) + c4] = v;
  }
}

extern "C" void kernel_launch(void* const* d_in, const int* in_sizes, int n_in,
                              void* d_out, int out_size, void* d_ws,
                              size_t ws_size, hipStream_t stream) {
  const float* xyz = (const float*)d_in[0];
  const float* feat = (const float*)d_in[1];
  float* sample_xyz = (float*)d_out;
  float* out_feat = (float*)d_out + (size_t)B_SZ * K_S * 3;

  hipLaunchKernelGGL(fps_kernel, dim3(B_SZ), dim3(FT), 0, stream, xyz,
                     sample_xyz);
  hipLaunchKernelGGL(group_kernel, dim3((B_SZ * K_S) / 4), dim3(256), 0,
                     stream, xyz, feat, sample_xyz, out_feat);
}

// Round 4
// 1699.544 us; speedup vs baseline: 1.3204x; 1.1903x over previous
//
#include <hip/hip_runtime.h>
#include <stdint.h>

#define N_PTS  16384
#define B_SZ   4
#define K_S    1024   // SAMPLE_NUM
#define K_N    32     // NEIGHBOR_NUM
#define C_FEAT 128

#define GRID3  8
#define NCELL  512    // 8^3 Morton cells
// per-batch workspace: rx,ry,rz (f32) + orig (u16), 16-byte aligned sections
#define WS_PER_B_BYTES (N_PTS * (3 * 4 + 2))   // 229376, %16 == 0

// ---------------- Threefry-2x32 (JAX-compatible) ----------------
__device__ inline void threefry2x32(uint32_t k0, uint32_t k1,
                                    uint32_t x0, uint32_t x1,
                                    uint32_t& o0, uint32_t& o1) {
  uint32_t ks[3] = {k0, k1, k0 ^ k1 ^ 0x1BD11BDAu};
  const uint32_t rot[2][4] = {{13u, 15u, 26u, 6u}, {17u, 29u, 16u, 24u}};
  x0 += ks[0];
  x1 += ks[1];
#pragma unroll
  for (int i = 0; i < 5; ++i) {
    const uint32_t* r = rot[i & 1];
#pragma unroll
    for (int j = 0; j < 4; ++j) {
      x0 += x1;
      x1 = (x1 << r[j]) | (x1 >> (32u - r[j]));
      x1 ^= x0;
    }
    x0 += ks[(i + 1) % 3];
    x1 += ks[(i + 2) % 3] + (uint32_t)(i + 1);
  }
  o0 = x0;
  o1 = x1;
}

// jax.random.randint(key(42),(B,),0,N), threefry_partitionable:
// k2 = TF((0,42),(0,1)); bits[b] = fold(TF(k2,(0,b))); start = bits & 16383
__device__ inline int fps_start_index(int b) {
  uint32_t c0, c1, h0, h1;
  threefry2x32(0u, 42u, 0u, 1u, c0, c1);
  threefry2x32(c0, c1, 0u, (uint32_t)b, h0, h1);
  return (int)((h0 ^ h1) & (uint32_t)(N_PTS - 1));
}

// ---------------- Morton bucket sort: one block per batch ----------------
__device__ inline uint32_t expand3(uint32_t v) {  // 3-bit -> bits 0,3,6
  return (v & 1u) | ((v & 2u) << 2) | ((v & 4u) << 4);
}

__global__ __launch_bounds__(1024) void bucket_kernel(
    const float* __restrict__ xyz, float* __restrict__ ws) {
  const int b = blockIdx.x;
  const int t = threadIdx.x;
  const float* bx = xyz + (size_t)b * N_PTS * 3;
  float* rx = (float*)((char*)ws + (size_t)b * WS_PER_B_BYTES);
  float* ry = rx + N_PTS;
  float* rz = ry + N_PTS;
  unsigned short* ro = (unsigned short*)(rz + N_PTS);

  __shared__ unsigned int cnt[NCELL];
  __shared__ unsigned int scn[NCELL];

  if (t < NCELL) cnt[t] = 0;
  __syncthreads();

  unsigned short cell[16];
#pragma unroll
  for (int j = 0; j < 16; ++j) {
    const int p = t + j * 1024;  // coalesced
    const float x = bx[p * 3 + 0];
    const float y = bx[p * 3 + 1];
    const float z = bx[p * 3 + 2];
    int ix = (int)(x * 8.0f); ix = ix > 7 ? 7 : (ix < 0 ? 0 : ix);
    int iy = (int)(y * 8.0f); iy = iy > 7 ? 7 : (iy < 0 ? 0 : iy);
    int iz = (int)(z * 8.0f); iz = iz > 7 ? 7 : (iz < 0 ? 0 : iz);
    const uint32_t code =
        expand3((uint32_t)ix) | (expand3((uint32_t)iy) << 1) |
        (expand3((uint32_t)iz) << 2);
    cell[j] = (unsigned short)code;
    atomicAdd(&cnt[code], 1u);
  }
  __syncthreads();

  // exclusive prefix sum over 512 counts (Hillis-Steele)
  unsigned int v0 = 0;
  if (t < NCELL) { v0 = cnt[t]; scn[t] = v0; }
  __syncthreads();
  for (int d = 1; d < NCELL; d <<= 1) {
    unsigned int add = 0;
    if (t < NCELL && t >= d) add = scn[t - d];
    __syncthreads();
    if (t < NCELL) scn[t] += add;
    __syncthreads();
  }
  if (t < NCELL) scn[t] -= v0;  // exclusive
  __syncthreads();

  // scatter (order within cell nondeterministic -- results invariant: the
  // FPS reduce is a commutative max over unique (value, ~orig_idx) keys)
#pragma unroll
  for (int j = 0; j < 16; ++j) {
    const int p = t + j * 1024;
    const unsigned int place = atomicAdd(&scn[cell[j]], 1u);
    rx[place] = bx[p * 3 + 0];
    ry[place] = bx[p * 3 + 1];
    rz[place] = bx[p * 3 + 2];
    ro[place] = (unsigned short)p;
  }
}

// ---------------- Bucketed FPS: one 1024-thread block per batch -----------
// Thread owns 16 Morton-contiguous points (tight bbox). Per iteration it
// skips the update when 0.999*lb(bbox) >= cached md-max -- provably exact
// (margin >> f32 rounding). Waves with no updating lane skip the shuffle
// reduce and republish a cached key.
#define FT  1024
#define PPT 16

__global__ __launch_bounds__(FT) void fps_kernel(
    const float* __restrict__ xyz, const float* __restrict__ ws,
    float* __restrict__ sample_xyz) {
  const int b = blockIdx.x;
  const int t = threadIdx.x;
  const int lane = t & 63;
  const int wv = t >> 6;  // 0..15
  const float* bx = xyz + (size_t)b * N_PTS * 3;
  const float* rx = (const float*)((const char*)ws + (size_t)b * WS_PER_B_BYTES);
  const float* ry = rx + N_PTS;
  const float* rz = ry + N_PTS;
  const unsigned short* ro = (const unsigned short*)(rz + N_PTS);

  float px[PPT], py[PPT], pz[PPT], md[PPT];
  const int base = t * PPT;
#pragma unroll
  for (int j = 0; j < PPT; ++j) {
    px[j] = rx[base + j];
    py[j] = ry[base + j];
    pz[j] = rz[base + j];
    md[j] = __int_as_float(0x7f800000);  // +inf
  }
  // packed original indices (2 x u16 per reg)
  uint32_t op[PPT / 2];
  {
    const uint4* rop = (const uint4*)(ro + base);  // 32B-aligned
    const uint4 o0 = rop[0], o1 = rop[1];
    op[0] = o0.x; op[1] = o0.y; op[2] = o0.z; op[3] = o0.w;
    op[4] = o1.x; op[5] = o1.y; op[6] = o1.z; op[7] = o1.w;
  }
  // tight per-thread bbox
  float bnx = px[0], bXx = px[0], bny = py[0], bXy = py[0],
        bnz = pz[0], bXz = pz[0];
#pragma unroll
  for (int j = 1; j < PPT; ++j) {
    bnx = fminf(bnx, px[j]); bXx = fmaxf(bXx, px[j]);
    bny = fminf(bny, py[j]); bXy = fmaxf(bXy, py[j]);
    bnz = fminf(bnz, pz[j]); bXz = fmaxf(bXz, pz[j]);
  }

  __shared__ unsigned long long wkey[2][FT / 64];

  {  // seed buffer 0 with the start index as winner
    const int start = fps_start_index(b);
    if (t < FT / 64)
      wkey[0][t] = (0xFFFFFFFFull << 32) |
                   (unsigned long long)(0xFFFFFFFFu - (uint32_t)start);
  }
  float bestv = __int_as_float(0x7f800000);  // cached md-max (forces 1st upd)
  uint32_t besti = 0;
  unsigned long long kwave = 0;
  __syncthreads();

  for (int s = 0; s < K_S; ++s) {
    const int rb = s & 1, wb = rb ^ 1;

    // cross-wave argmax: lane-parallel butterfly over the 16 wave keys
    unsigned long long best = wkey[rb][lane & 15];
#pragma unroll
    for (int off = 1; off < 16; off <<= 1) {
      const unsigned long long o = __shfl_xor(best, off, 64);
      best = (o > best) ? o : best;
    }
    const int cur = (int)(0xFFFFFFFFu - (uint32_t)best);

    // broadcast load of winner coords (original-order array)
    const float cx = bx[cur * 3 + 0];
    const float cy = bx[cur * 3 + 1];
    const float cz = bx[cur * 3 + 2];
    if (t == 0) {
      float* o = sample_xyz + ((size_t)b * K_S + s) * 3;
      o[0] = cx; o[1] = cy; o[2] = cz;
    }

    // conservative squared lower bound to this thread's bbox
    const float dlx = fmaxf(fmaxf(__fsub_rn(bnx, cx), __fsub_rn(cx, bXx)), 0.f);
    const float dly = fmaxf(fmaxf(__fsub_rn(bny, cy), __fsub_rn(cy, bXy)), 0.f);
    const float dlz = fmaxf(fmaxf(__fsub_rn(bnz, cz), __fsub_rn(cz, bXz)), 0.f);
    const float lb = dlx * dlx + dly * dly + dlz * dlz;
    const bool upd = (lb * 0.999f) < bestv;

    if (__any(upd)) {
      if (upd) {
        float bv = -1.0f;
        uint32_t bi = 0;
#pragma unroll
        for (int j = 0; j < PPT; ++j) {
          const float dx = __fsub_rn(px[j], cx);
          const float dy = __fsub_rn(py[j], cy);
          const float dz = __fsub_rn(pz[j], cz);
          // XLA order: ((dx*dx + dy*dy) + dz*dz), no FMA contraction
          const float d2 = __fadd_rn(
              __fadd_rn(__fmul_rn(dx, dx), __fmul_rn(dy, dy)),
              __fmul_rn(dz, dz));
          const float m = fminf(md[j], d2);
          md[j] = m;
          const uint32_t orig =
              (j & 1) ? (op[j >> 1] >> 16) : (op[j >> 1] & 0xFFFFu);
          const bool better = (m > bv) | ((m == bv) & (orig < bi));
          bv = better ? m : bv;
          bi = better ? orig : bi;
        }
        bestv = bv;
        besti = bi;
      }
      // wave reduce over all 64 lanes (fresh or cached keys)
      unsigned long long k =
          ((unsigned long long)__float_as_uint(bestv) << 32) |
          (unsigned long long)(0xFFFFFFFFu - besti);
#pragma unroll
      for (int off = 1; off < 64; off <<= 1) {
        const unsigned long long o = __shfl_xor(k, off, 64);
        k = (o > k) ? o : k;
      }
      kwave = k;
    }
    if (lane == 0) wkey[wb][wv] = kwave;
    __syncthreads();  // one barrier per iteration (double-buffered keys)
  }
}

// ---------------- Ball query + gather: one wave per query ----------------
__global__ __launch_bounds__(256) void group_kernel(
    const float* __restrict__ xyz, const float* __restrict__ feat,
    const float* __restrict__ sample_xyz, float* __restrict__ out_feat) {
  const int lane = threadIdx.x & 63;
  const int wv = threadIdx.x >> 6;
  const int q = blockIdx.x * 4 + wv;  // 0..4095
  const int b = q >> 10;

  __shared__ int idxs[4][K_N];

  const float qx = sample_xyz[q * 3 + 0];
  const float qy = sample_xyz[q * 3 + 1];
  const float qz = sample_xyz[q * 3 + 2];
  const float* bx = xyz + (size_t)b * N_PTS * 3;
  const float R2 = (float)(0.2 * 0.2);  // f32 round of the Python double
  const unsigned long long below = (1ull << lane) - 1ull;

  int cnt = 0;
  for (int c = 0; c < N_PTS / 128 && cnt < K_N; ++c) {
    const int p0 = c * 128 + lane;
    const int p1 = p0 + 64;
    const float x0 = bx[p0 * 3 + 0], y0 = bx[p0 * 3 + 1], z0 = bx[p0 * 3 + 2];
    const float x1 = bx[p1 * 3 + 0], y1 = bx[p1 * 3 + 1], z1 = bx[p1 * 3 + 2];

    const float dx0 = __fsub_rn(qx, x0), dy0 = __fsub_rn(qy, y0),
                dz0 = __fsub_rn(qz, z0);
    const float d20 = __fadd_rn(
        __fadd_rn(__fmul_rn(dx0, dx0), __fmul_rn(dy0, dy0)),
        __fmul_rn(dz0, dz0));
    const float dx1 = __fsub_rn(qx, x1), dy1 = __fsub_rn(qy, y1),
                dz1 = __fsub_rn(qz, z1);
    const float d21 = __fadd_rn(
        __fadd_rn(__fmul_rn(dx1, dx1), __fmul_rn(dy1, dy1)),
        __fmul_rn(dz1, dz1));

    const bool h0 = d20 < R2;
    const bool h1 = d21 < R2;
    const unsigned long long m0 = __ballot(h0);
    const unsigned long long m1 = __ballot(h1);
    const int c0 = (int)__popcll(m0);
    if (h0) {
      const int slot = cnt + (int)__popcll(m0 & below);
      if (slot < K_N) idxs[wv][slot] = p0;
    }
    if (h1) {
      const int slot = cnt + c0 + (int)__popcll(m1 & below);
      if (slot < K_N) idxs[wv][slot] = p1;
    }
    cnt += c0 + (int)__popcll(m1);
  }
  // -1 padding semantics: gather_feat maps -1 -> row SAMPLE_NUM (=1024)
  if (cnt < K_N) {
    for (int s2 = cnt + lane; s2 < K_N; s2 += 64) idxs[wv][s2] = K_S;
  }
  __syncthreads();

  // gather feat rows -> out[(q*32 + k)*128 + c], float4 coalesced, full unroll
  const float4* f4 = (const float4*)feat;
  float4* o4 = (float4*)out_feat;
  const size_t fbase = (size_t)b * N_PTS * (C_FEAT / 4);
  const size_t obase = (size_t)q * K_N * (C_FEAT / 4);
  const int c4 = lane & 31;
  const int khalf = lane >> 5;
#pragma unroll
  for (int kk = 0; kk < K_N; kk += 2) {
    const int k = kk + khalf;
    const int id = idxs[wv][k];
    const float4 v = f4[fbase + (size_t)id * (C_FEAT / 4) + c4];
    o4[obase + (size_t)k * (C_FEAT / 4) + c4] = v;
  }
}

extern "C" void kernel_launch(void* const* d_in, const int* in_sizes, int n_in,
                              void* d_out, int out_size, void* d_ws,
                              size_t ws_size, hipStream_t stream) {
  const float* xyz = (const float*)d_in[0];
  const float* feat = (const float*)d_in[1];
  float* sample_xyz = (float*)d_out;
  float* out_feat = (float*)d_out + (size_t)B_SZ * K_S * 3;
  float* ws = (float*)d_ws;

  hipLaunchKernelGGL(bucket_kernel, dim3(B_SZ), dim3(1024), 0, stream, xyz, ws);
  hipLaunchKernelGGL(fps_kernel, dim3(B_SZ), dim3(FT), 0, stream, xyz, ws,
                     sample_xyz);
  hipLaunchKernelGGL(group_kernel, dim3((B_SZ * K_S) / 4), dim3(256), 0,
                     stream, xyz, feat, sample_xyz, out_feat);
}